// Round 4
// baseline (75.703 us; speedup 1.0000x reference)
//
#include <hip/hip_runtime.h>

#define RNODES 1152
#define KDIM 9216                 // 1152*8
#define COUT 16
#define NCAPS 10
#define WSTRIDE (KDIM*COUT)       // 147456 floats per capsule

#define SPLITS 32
#define STEPS 9                   // 9*32 = 288 k per split
#define MT 16                     // rows per gemm block
#define GBLK 512                  // 16 mt x 32 ks  (2 blocks/CU)
#define PARTL (MT*COUT*NCAPS)     // 2560 floats per block partial
#define PARTL4 (PARTL/4)

// ---- ws layout (bytes). Total 12.9 MB of the 256 MiB workspace. ----
// xab: x as bf16, fragment-interleaved [bt(16)][kb(1152)][br(16)][8k]  (16B units)
// wt : W as bf16, fragment-interleaved [n(10)][kb(1152)][o(16)][8k]
#define XAB_UNITS (16*1152*16)            // 294912 16B units
#define WT_OFF   ((size_t)XAB_UNITS*16)   // 4718592
#define WT_UNITS (NCAPS*1152*16)          // 184320 16B units
#define PART_OFF (WT_OFF + (size_t)WT_UNITS*16)   // 7667712 (16B aligned)

using bf16x8 = __attribute__((ext_vector_type(8))) short;
using f32x4  = __attribute__((ext_vector_type(4))) float;

// round-to-nearest (ties up): same rounding as R8/R11 -> identical bf16 values.
__device__ __forceinline__ unsigned short f2bf(float f) {
  unsigned int u = __builtin_bit_cast(unsigned int, f);
  return (unsigned short)((u + 0x8000u) >> 16);
}

__device__ __forceinline__ void pack_store8(unsigned short* dst, const float* v) {
  union { unsigned short us[8]; uint4 q; } t;
#pragma unroll
  for (int i = 0; i < 8; ++i) t.us[i] = f2bf(v[i]);
  *(uint4*)dst = t.q;
}

// R12 kernel 1: one streaming pass converts BOTH operands to bf16 in MFMA
// fragment order. This removes the 16x-redundant per-block W transpose+convert
// (R8/R11's LDS staging) from the gemm entirely. Pure streaming, ~7 waves/SIMD,
// no dependencies -> runs at HBM BW (the resource the fills prove is available).
// blocks 0..1151: x -> xab.  unit u = bt*18432 + kb*16 + br  (72 blocks per bt)
// blocks 1152..1871: W -> wt. unit u = n*18432 + kb*16 + o   (72 blocks per n)
__global__ __launch_bounds__(256) void caps_convert(const float* __restrict__ x,
                                                    const float* __restrict__ W,
                                                    unsigned short* __restrict__ wsb) {
  const int bx = blockIdx.x, tid = threadIdx.x;
  if (bx < 1152) {
    const int bt = bx / 72;                       // scalar (magic-mul on SALU)
    const int r  = (bx % 72) * 256 + tid;         // 0..18431 = kb*16+br
    const int kb = r >> 4, br = r & 15;
    const float* src = x + (size_t)(bt * 16 + br) * KDIM + kb * 8;
    float4 v0 = *(const float4*)src;
    float4 v1 = *(const float4*)(src + 4);
    float v[8] = {v0.x, v0.y, v0.z, v0.w, v1.x, v1.y, v1.z, v1.w};
    pack_store8(wsb + ((size_t)bt * 18432 + r) * 8, v);
  } else {
    const int b2 = bx - 1152;
    const int n  = b2 / 72;
    const int r  = (b2 % 72) * 256 + tid;         // kb*16 + o
    const int kb = r >> 4, o = r & 15;
    const float* src = W + (size_t)n * WSTRIDE + (size_t)kb * 128 + o;  // W[n][kb*8][o]
    float v[8];
#pragma unroll
    for (int j = 0; j < 8; ++j) v[j] = src[j * 16];   // k-stride = COUT
    pack_store8(wsb + (WT_OFF / 2) + ((size_t)n * 18432 + r) * 8, v);
  }
}

// R12 kernel 2: the gemm with ALL staging machinery deleted. No LDS, no
// __syncthreads, no f2bf in the loop, no address VALU (constant offsets fold
// into the load immediates). Per thread: 36 global_load_dwordx4 (each a fully
// contiguous 1KB wave transaction thanks to the fragment-interleaved layouts)
// + 27 MFMA, double-buffered in 3-step groups (static buffer names - no
// runtime-indexed arrays). bid = mt*32+ks keeps the R8 XCD property: the 16
// mt-blocks sharing W-slice ks sit on one XCD -> wt re-reads are L2 hits.
// Per-capsule accumulation order is s=0..8 ascending, identical to R11 ->
// partials are bitwise-identical to R11's.
__global__ __launch_bounds__(256, 2) void caps_gemm(const unsigned short* __restrict__ xab,
                                                    const unsigned short* __restrict__ wt,
                                                    float* __restrict__ part) {
  const int tid  = threadIdx.x, bid = blockIdx.x;
  const int mt   = bid >> 5;         // 0..15
  const int ks   = bid & 31;         // 0..31
  const int lane = tid & 63;
  const int wv   = tid >> 6;         // 0..3: capsule-triple slot
  const int q    = lane >> 4;        // k-quad: frag k = q*8 + j
  const int m16  = lane & 15;        // A: batch row / B: o / C: o
  const int kb0  = ks * (STEPS * 4); // 36 kb-units of 8k

  // lane base pointers; step s advances kb by 4 -> +512 ushorts (+1024B)
  const unsigned short* ap = xab + ((size_t)(mt * 1152 + kb0 + q) * 16 + m16) * 8;
  const unsigned short* bp0, *bp1, *bp2;
  int nt[3];
#pragma unroll
  for (int j = 0; j < 3; ++j) nt[j] = wv * 3 + j;   // 9,10,11 on wv=3: 10,11 dead
  {
    const int n0 = nt[0] < NCAPS ? nt[0] : 0;
    const int n1 = nt[1] < NCAPS ? nt[1] : 0;
    const int n2 = nt[2] < NCAPS ? nt[2] : 0;
    bp0 = wt + ((size_t)(n0 * 1152 + kb0 + q) * 16 + m16) * 8;
    bp1 = wt + ((size_t)(n1 * 1152 + kb0 + q) * 16 + m16) * 8;
    bp2 = wt + ((size_t)(n2 * 1152 + kb0 + q) * 16 + m16) * 8;
  }

  f32x4 acc[3];
#pragma unroll
  for (int i = 0; i < 3; ++i) acc[i] = (f32x4){0.f, 0.f, 0.f, 0.f};

  bf16x8 aA[3], aB[3], bA[3][3], bB[3][3];

  auto loadg = [&](bf16x8 (&AF)[3], bf16x8 (&BF)[3][3], int g) {
#pragma unroll
    for (int s = 0; s < 3; ++s) {
      const int off = (g * 3 + s) * 512;
      AF[s]    = *(const bf16x8*)(ap  + off);
      BF[0][s] = *(const bf16x8*)(bp0 + off);
      BF[1][s] = *(const bf16x8*)(bp1 + off);
      BF[2][s] = *(const bf16x8*)(bp2 + off);
    }
  };
  auto mmag = [&](bf16x8 (&AF)[3], bf16x8 (&BF)[3][3]) {
#pragma unroll
    for (int s = 0; s < 3; ++s)
#pragma unroll
      for (int j = 0; j < 3; ++j)
        acc[j] = __builtin_amdgcn_mfma_f32_16x16x32_bf16(AF[s], BF[j][s], acc[j], 0, 0, 0);
  };

  loadg(aA, bA, 0);         // 12 loads in flight
  loadg(aB, bB, 1);         // +12
  mmag(aA, bA);             // waits group 0 only
  loadg(aA, bA, 2);
  mmag(aB, bB);
  mmag(aA, bA);

  // ---- partial store: P[bid][n][row16][o] — identical indexing to R11 ----
  float* P = part + (size_t)bid * PARTL;
#pragma unroll
  for (int j = 0; j < 3; ++j) {
    if (nt[j] < NCAPS) {
#pragma unroll
      for (int r = 0; r < 4; ++r)
        P[nt[j] * (MT * COUT) + (q * 4 + r) * COUT + m16] = acc[j][r];
    }
  }
}

// R11's reducer, verbatim (bitwise-identical output): thread f owns output
// float4 f, sums 32 splits in fixed order, squashes over 4-lane o-groups.
__global__ __launch_bounds__(128, 1) void caps_reduce(const float* __restrict__ ws,
                                                      float* __restrict__ out) {
  const int f  = blockIdx.x * 128 + threadIdx.x;   // 0..10239
  const int n  = f >> 10;
  const int b  = (f >> 2) & 255;
  const int o4 = f & 3;
  const int mt = b >> 4, row = b & 15;

  const float4* base = (const float4*)ws + (size_t)(mt * SPLITS) * PARTL4
                       + n * (MT * COUT / 4) + row * 4 + o4;
  float4 s0 = {0,0,0,0}, s1 = {0,0,0,0}, s2 = {0,0,0,0}, s3 = {0,0,0,0};
#pragma unroll
  for (int kk = 0; kk < SPLITS; kk += 4) {
    float4 a0 = base[(size_t)(kk + 0) * PARTL4];
    float4 a1 = base[(size_t)(kk + 1) * PARTL4];
    float4 a2 = base[(size_t)(kk + 2) * PARTL4];
    float4 a3 = base[(size_t)(kk + 3) * PARTL4];
    s0.x += a0.x; s0.y += a0.y; s0.z += a0.z; s0.w += a0.w;
    s1.x += a1.x; s1.y += a1.y; s1.z += a1.z; s1.w += a1.w;
    s2.x += a2.x; s2.y += a2.y; s2.z += a2.z; s2.w += a2.w;
    s3.x += a3.x; s3.y += a3.y; s3.z += a3.z; s3.w += a3.w;
  }
  const float inv = 1.0f / (float)RNODES;
  float4 s;
  s.x = ((s0.x + s1.x) + (s2.x + s3.x)) * inv;
  s.y = ((s0.y + s1.y) + (s2.y + s3.y)) * inv;
  s.z = ((s0.z + s1.z) + (s2.z + s3.z)) * inv;
  s.w = ((s0.w + s1.w) + (s2.w + s3.w)) * inv;

  float sq = s.x * s.x + s.y * s.y + s.z * s.z + s.w * s.w;
  sq += __shfl_xor(sq, 1);
  sq += __shfl_xor(sq, 2);
  const float g = sqrtf(sq) / (1.0f + sq);
  s.x *= g; s.y *= g; s.z *= g; s.w *= g;

  ((float4*)out)[f] = s;
}

extern "C" void kernel_launch(void* const* d_in, const int* in_sizes, int n_in,
                              void* d_out, int out_size, void* d_ws, size_t ws_size,
                              hipStream_t stream) {
  const float* x = (const float*)d_in[0];   // [256,1152,8] fp32
  const float* W = (const float*)d_in[1];   // [10,1152,8,16] fp32
  float* out = (float*)d_out;               // 40960 fp32

  unsigned short* wsb  = (unsigned short*)d_ws;
  const unsigned short* xab = (const unsigned short*)d_ws;
  const unsigned short* wt  = (const unsigned short*)((const char*)d_ws + WT_OFF);
  float* part = (float*)((char*)d_ws + PART_OFF);

  caps_convert<<<dim3(1872), dim3(256), 0, stream>>>(x, W, wsb);
  caps_gemm<<<dim3(GBLK), dim3(256), 0, stream>>>(xab, wt, part);
  caps_reduce<<<dim3(80), dim3(128), 0, stream>>>(part, out);
}

// Round 5
// 74.751 us; speedup vs baseline: 1.0127x; 1.0127x over previous
//
#include <hip/hip_runtime.h>

#define RNODES 1152
#define KDIM 9216                 // 1152*8
#define COUT 16
#define NCAPS 10
#define WSTRIDE (KDIM*COUT)       // 147456 floats per capsule

// ---- ws layout (bytes). Total 7.7 MB of the 256 MiB workspace. ----
// xab: x as bf16, fragment-interleaved [bt(16)][kb(1152)][br(16)][8k]  (16B units)
// wt : W as bf16, fragment-interleaved [n(10)][kb(1152)][o(16)][8k]
#define XAB_UNITS (16*1152*16)            // 294912 16B units
#define WT_OFF   ((size_t)XAB_UNITS*16)   // 4718592

using bf16x8 = __attribute__((ext_vector_type(8))) short;
using f32x4  = __attribute__((ext_vector_type(4))) float;

// round-to-nearest (ties up): same rounding as R8..R12 -> identical bf16 values.
__device__ __forceinline__ unsigned short f2bf(float f) {
  unsigned int u = __builtin_bit_cast(unsigned int, f);
  return (unsigned short)((u + 0x8000u) >> 16);
}

__device__ __forceinline__ void pack_store8(unsigned short* dst, const float* v) {
  union { unsigned short us[8]; uint4 q; } t;
#pragma unroll
  for (int i = 0; i < 8; ++i) t.us[i] = f2bf(v[i]);
  *(uint4*)dst = t.q;
}

// R13 kernel 1: VERBATIM R12 convert (proven bitwise-correct). One streaming
// pass converts both operands to bf16 in MFMA fragment order. ~23 MB traffic,
// pure BW-bound.
__global__ __launch_bounds__(256) void caps_convert(const float* __restrict__ x,
                                                    const float* __restrict__ W,
                                                    unsigned short* __restrict__ wsb) {
  const int bx = blockIdx.x, tid = threadIdx.x;
  if (bx < 1152) {
    const int bt = bx / 72;
    const int r  = (bx % 72) * 256 + tid;         // 0..18431 = kb*16+br
    const int kb = r >> 4, br = r & 15;
    const float* src = x + (size_t)(bt * 16 + br) * KDIM + kb * 8;
    float4 v0 = *(const float4*)src;
    float4 v1 = *(const float4*)(src + 4);
    float v[8] = {v0.x, v0.y, v0.z, v0.w, v1.x, v1.y, v1.z, v1.w};
    pack_store8(wsb + ((size_t)bt * 18432 + r) * 8, v);
  } else {
    const int b2 = bx - 1152;
    const int n  = b2 / 72;
    const int r  = (b2 % 72) * 256 + tid;         // kb*16 + o
    const int kb = r >> 4, o = r & 15;
    const float* src = W + (size_t)n * WSTRIDE + (size_t)kb * 128 + o;  // W[n][kb*8][o]
    float v[8];
#pragma unroll
    for (int j = 0; j < 8; ++j) v[j] = src[j * 16];   // k-stride = COUT
    pack_store8(wsb + (WT_OFF / 2) + ((size_t)n * 18432 + r) * 8, v);
  }
}

// R13 kernel 2: full-K mono-GEMM. NO workspace partials, NO reduce kernel, NO
// barriers in the main loop, NO in-loop VALU.
//  * grid 160 x 1024: block = (capsule n = bid>>4, mt = bid&15). bid%8 = mt%8
//    -> the 10 capsule-blocks sharing an x mt-slice sit on ONE XCD (xab L2-hot);
//    wt (2.95 MB) is L3-resident for cross-XCD re-reads.
//  * 16 waves split K=9216 into private 576-chunks: 18 MFMA steps each, single
//    f32x4 accumulator, 3x3 register double-buffer (static names) so >=9 loads
//    are always in flight -> HBM/L2 latency hidden without any LDS.
//  * Per step: 1 A-load + 1 B-load (fragment-interleaved 16B, fully coalesced
//    1KB wave txns) + 1 MFMA. Constant offsets fold into load immediates.
//  * Tail: 16-wave fixed-order pairwise LDS reduce (deterministic), squash over
//    16-lane o-groups, coalesced store straight to out.
__global__ __launch_bounds__(1024, 1) void caps_mono(const unsigned short* __restrict__ xab,
                                                     const unsigned short* __restrict__ wt,
                                                     float* __restrict__ out) {
  __shared__ float redbuf[16][256];               // 16 KB

  const int tid  = threadIdx.x, bid = blockIdx.x;
  const int n    = bid >> 4;         // capsule 0..9
  const int mt   = bid & 15;         // m-tile 0..15
  const int wv   = tid >> 6;         // 0..15: private 576-k chunk
  const int lane = tid & 63;
  const int q    = lane >> 4;        // k-quad: frag k = q*8 + j
  const int m16  = lane & 15;        // A: batch row / B: o / C: o
  const int kb0  = wv * 72;          // 72 kb-units of 8k per wave

  const unsigned short* ap = xab + ((size_t)(mt * 1152 + kb0 + q) * 16 + m16) * 8;
  const unsigned short* bp = wt  + ((size_t)(n  * 1152 + kb0 + q) * 16 + m16) * 8;

  f32x4 acc = (f32x4){0.f, 0.f, 0.f, 0.f};
  bf16x8 aA[3], bA[3], aB[3], bB[3];

  auto loadg = [&](bf16x8 (&A)[3], bf16x8 (&B)[3], int g) {
#pragma unroll
    for (int s = 0; s < 3; ++s) {
      const int off = (g * 3 + s) * 512;          // 4 kb-units per step
      A[s] = *(const bf16x8*)(ap + off);
      B[s] = *(const bf16x8*)(bp + off);
    }
  };
  auto mmag = [&](bf16x8 (&A)[3], bf16x8 (&B)[3]) {
#pragma unroll
    for (int s = 0; s < 3; ++s)
      acc = __builtin_amdgcn_mfma_f32_16x16x32_bf16(A[s], B[s], acc, 0, 0, 0);
  };

  loadg(aA, bA, 0);
  loadg(aB, bB, 1);
  mmag(aA, bA); loadg(aA, bA, 2);
  mmag(aB, bB); loadg(aB, bB, 3);
  mmag(aA, bA); loadg(aA, bA, 4);
  mmag(aB, bB); loadg(aB, bB, 5);
  mmag(aA, bA);
  mmag(aB, bB);

  // ---- tail: 16-wave fixed pairwise reduce, squash, store ----
  // C/D layout: col = m16 (=o), row = q*4 + r  ->  16x16 tile index (row*16+o)
#pragma unroll
  for (int r = 0; r < 4; ++r)
    redbuf[wv][(q * 4 + r) * 16 + m16] = acc[r];
  __syncthreads();

  if (tid < 256) {
    float r0  = redbuf[0][tid],  r1  = redbuf[1][tid];
    float r2  = redbuf[2][tid],  r3  = redbuf[3][tid];
    float r4  = redbuf[4][tid],  r5  = redbuf[5][tid];
    float r6  = redbuf[6][tid],  r7  = redbuf[7][tid];
    float r8  = redbuf[8][tid],  r9  = redbuf[9][tid];
    float r10 = redbuf[10][tid], r11 = redbuf[11][tid];
    float r12 = redbuf[12][tid], r13 = redbuf[13][tid];
    float r14 = redbuf[14][tid], r15 = redbuf[15][tid];
    const float lo = ((r0 + r1) + (r2 + r3)) + ((r4 + r5) + (r6 + r7));
    const float hi = ((r8 + r9) + (r10 + r11)) + ((r12 + r13) + (r14 + r15));
    const float v  = (lo + hi) * (1.0f / (float)RNODES);

    float sq = v * v;                 // squash over the 16-lane o-group
    sq += __shfl_xor(sq, 1);
    sq += __shfl_xor(sq, 2);
    sq += __shfl_xor(sq, 4);
    sq += __shfl_xor(sq, 8);
    const float g = sqrtf(sq) / (1.0f + sq);

    out[n * 4096 + (mt * 16 + (tid >> 4)) * 16 + (tid & 15)] = v * g;
  }
}

extern "C" void kernel_launch(void* const* d_in, const int* in_sizes, int n_in,
                              void* d_out, int out_size, void* d_ws, size_t ws_size,
                              hipStream_t stream) {
  const float* x = (const float*)d_in[0];   // [256,1152,8] fp32
  const float* W = (const float*)d_in[1];   // [10,1152,8,16] fp32
  float* out = (float*)d_out;               // 40960 fp32

  unsigned short* wsb  = (unsigned short*)d_ws;
  const unsigned short* xab = (const unsigned short*)d_ws;
  const unsigned short* wt  = (const unsigned short*)((const char*)d_ws + WT_OFF);

  caps_convert<<<dim3(1872), dim3(256), 0, stream>>>(x, W, wsb);
  caps_mono<<<dim3(160), dim3(1024), 0, stream>>>(xab, wt, out);
}

// Round 6
// 71.132 us; speedup vs baseline: 1.0643x; 1.0509x over previous
//
#include <hip/hip_runtime.h>

#define RNODES 1152
#define KDIM 9216                 // 1152*8
#define COUT 16
#define NCAPS 10
#define WSTRIDE (KDIM*COUT)       // 147456 floats per capsule

#define LROW 40                   // 32 k + 8 pad (ushorts) -> 80B rows, 16B-aligned reads
#define WBUF (NCAPS*COUT*LROW)    // 6400 ushorts = 12.8 KB per buffer
#define STEPS 9                   // k-steps of 32 per block
#define SPLITS 32                 // 32 * 9 * 32 = 9216 = KDIM
#define NBLK 256                  // 8 M-tiles x 32 splits = 1 block/CU exactly
#define PARTL (32*COUT*NCAPS)     // 5120 floats per block partial (32 rows)
#define PARTL4 (PARTL/4)          // 1280 float4

using bf16x8 = __attribute__((ext_vector_type(8))) short;
using f32x4  = __attribute__((ext_vector_type(4))) float;

// round-to-nearest (ties up): 2 VALU ops; unbiased to 2^-9 rel — same as R6.
__device__ __forceinline__ unsigned short f2bf(float f) {
  unsigned int u = __builtin_bit_cast(unsigned int, f);
  return (unsigned short)((u + 0x8000u) >> 16);
}

// R14 = R8 verbatim (measured best, 71.2 µs). Cross-round evidence (R9..R13):
// the timed window is ~42 µs harness re-poison fill (BW-saturated) + ~22 µs
// fixed dispatch overhead + kernels; R8's kernel pair (~8 µs) is within ~5% of
// the mandatory-traffic floor, and every structural deviation tried (coop
// fusion, full-K mono, 2 blk/CU, pre-converted operands) measured worse.
//
// grid = 256 (one block/CU). bid = mt*32 + ks -> XCD = ks%8: all 8 mt-blocks
// sharing W-slice ks sit on ONE XCD -> W re-reads are L2 hits.
//  * W staging decode is slab-contiguous: unit u = j*256+tid -> n=u>>7,
//    kl=(u&127)>>2, o4=(u&3)*4. Consecutive lanes read consecutive 16B ->
//    every W load is a 1KB fully-coalesced wave transaction.
//  * LDS layout adds an 8-element k-block rotation so the write pattern
//    stays conflict-free: col c stores k-block t at ((t + (c&3) + ((c>>2)&3))&3).
//    Writes 2-way bank aliasing (free); reads b128 16B-aligned at
//    qrot = (q + (m16&3) + (m16>>2)) & 3 — capsule-independent, conflict-free.
__global__ __launch_bounds__(256, 1) void caps_gemm(const float* __restrict__ x,
                                                    const float* __restrict__ W,
                                                    float* __restrict__ ws) {
  __shared__ unsigned short wbuf[2][WBUF];   // ping-pong, 25.6 KB
  const int tid = threadIdx.x;
  const int bid = blockIdx.x;
  const int mt  = bid >> 5;         // 0..7  (32-row M-tile)
  const int ks  = bid & 31;         // 0..31 (K split)
  const int b0  = mt * 32;
  const int k0  = ks * (STEPS * 32);   // 288-element K chunk

  const int lane = tid & 63;
  const int wv   = tid >> 6;
  const int p    = wv >> 1;         // row half
  const int h    = wv & 1;          // capsule half
  const int q    = lane >> 4;       // k-quad
  const int m16  = lane & 15;

  // ---- slab-contiguous staging decode (5 units/thread covers 1280 float4) ----
  int u_n[5], u_kl[5], u_of[5];
#pragma unroll
  for (int j = 0; j < 5; ++j) {
    const int u  = j * 256 + tid;
    u_n[j]  = u >> 7;               // capsule slab 0..9
    const int rem = u & 127;
    u_kl[j] = rem >> 2;             // k within step, 0..31
    u_of[j] = (rem & 3) << 2;       // o-quad base 0,4,8,12
  }

  const float* xrow = x + (size_t)(b0 + p * 16 + m16) * KDIM + k0 + q * 8;

  float4 pw[3][5];
  float4 pa[3][2];

  auto load_step = [&](int s, int slot) {
#pragma unroll
    for (int j = 0; j < 5; ++j)
      pw[slot][j] = *(const float4*)(W + (size_t)u_n[j] * WSTRIDE +
                                     (size_t)(k0 + s * 32 + u_kl[j]) * COUT + u_of[j]);
    pa[slot][0] = *(const float4*)(xrow + s * 32);
    pa[slot][1] = *(const float4*)(xrow + s * 32 + 4);
  };

  load_step(0, 0);
  load_step(1, 1);
  load_step(2, 2);

  f32x4 acc[5];
#pragma unroll
  for (int i = 0; i < 5; ++i) acc[i] = (f32x4){0.f, 0.f, 0.f, 0.f};

  // per-lane rotated read quad (k-block) — same for every capsule
  const int qrot = (q + (m16 & 3) + (m16 >> 2)) & 3;

#pragma unroll
  for (int s = 0; s < STEPS; ++s) {
    const int slot = s % 3;
    unsigned short* b = &wbuf[s & 1][0];
    // stage W step s: [col][k-rotated] bf16 transpose
#pragma unroll
    for (int j = 0; j < 5; ++j) {
      const int kl  = u_kl[j];
      const int klo = kl & 7, kblk = kl >> 3;
      const float* v = (const float*)&pw[slot][j];
#pragma unroll
      for (int r = 0; r < 4; ++r) {
        const int c   = u_n[j] * COUT + u_of[j] + r;
        const int pos = klo | (((kblk + (c & 3) + ((c >> 2) & 3)) & 3) << 3);
        b[c * LROW + pos] = f2bf(v[r]);
      }
    }
    __syncthreads();
    // write(s+2) to this parity happens after barrier(s+1); reads(s) drain
    // before barrier(s+1) -> classic 2-buffer safety, 1 barrier/step.

    bf16x8 a;
    a[0] = (short)f2bf(pa[slot][0].x); a[1] = (short)f2bf(pa[slot][0].y);
    a[2] = (short)f2bf(pa[slot][0].z); a[3] = (short)f2bf(pa[slot][0].w);
    a[4] = (short)f2bf(pa[slot][1].x); a[5] = (short)f2bf(pa[slot][1].y);
    a[6] = (short)f2bf(pa[slot][1].z); a[7] = (short)f2bf(pa[slot][1].w);

    if (s + 3 < STEPS) load_step(s + 3, slot);   // slot just freed

#pragma unroll
    for (int j = 0; j < 5; ++j) {
      const int nt = h * 5 + j;
      bf16x8 bf = *(const bf16x8*)&b[(nt * COUT + m16) * LROW + (qrot << 3)];
      acc[j] = __builtin_amdgcn_mfma_f32_16x16x32_bf16(a, bf, acc[j], 0, 0, 0);
    }
  }

  // ---- partial store: P[bid][n][row32][o] ----
  float* P = ws + (size_t)bid * PARTL;
  const int prow = p * 16 + q * 4;   // C/D: col=lane&15 (=o), row=q*4+reg
#pragma unroll
  for (int j = 0; j < 5; ++j)
#pragma unroll
    for (int r = 0; r < 4; ++r)
      P[(h * 5 + j) * 512 + (prow + r) * COUT + m16] = acc[j][r];
}

// grid = 80 x 128: thread f owns output float4 f (f = n*1024 + b*4 + o4),
// sums 32 splits with fixed order (deterministic), squashes over 4-lane o-groups.
__global__ __launch_bounds__(128, 1) void caps_reduce(const float* __restrict__ ws,
                                                      float* __restrict__ out) {
  const int f  = blockIdx.x * 128 + threadIdx.x;   // 0..10239
  const int n  = f >> 10;
  const int b  = (f >> 2) & 255;
  const int o4 = f & 3;
  const int mt = b >> 5, row = b & 31;

  const float4* base = (const float4*)ws + (size_t)(mt * SPLITS) * PARTL4
                       + n * 128 + row * 4 + o4;
  float4 s0 = {0,0,0,0}, s1 = {0,0,0,0}, s2 = {0,0,0,0}, s3 = {0,0,0,0};
#pragma unroll
  for (int kk = 0; kk < SPLITS; kk += 4) {
    float4 a0 = base[(size_t)(kk + 0) * PARTL4];
    float4 a1 = base[(size_t)(kk + 1) * PARTL4];
    float4 a2 = base[(size_t)(kk + 2) * PARTL4];
    float4 a3 = base[(size_t)(kk + 3) * PARTL4];
    s0.x += a0.x; s0.y += a0.y; s0.z += a0.z; s0.w += a0.w;
    s1.x += a1.x; s1.y += a1.y; s1.z += a1.z; s1.w += a1.w;
    s2.x += a2.x; s2.y += a2.y; s2.z += a2.z; s2.w += a2.w;
    s3.x += a3.x; s3.y += a3.y; s3.z += a3.z; s3.w += a3.w;
  }
  const float inv = 1.0f / (float)RNODES;
  float4 s;
  s.x = ((s0.x + s1.x) + (s2.x + s3.x)) * inv;
  s.y = ((s0.y + s1.y) + (s2.y + s3.y)) * inv;
  s.z = ((s0.z + s1.z) + (s2.z + s3.z)) * inv;
  s.w = ((s0.w + s1.w) + (s2.w + s3.w)) * inv;

  float sq = s.x * s.x + s.y * s.y + s.z * s.z + s.w * s.w;
  sq += __shfl_xor(sq, 1);   // o-group of 16 = 4 adjacent lanes (o4 = f&3)
  sq += __shfl_xor(sq, 2);
  const float g = sqrtf(sq) / (1.0f + sq);
  s.x *= g; s.y *= g; s.z *= g; s.w *= g;

  ((float4*)out)[f] = s;     // out float4 index == f by construction
}

extern "C" void kernel_launch(void* const* d_in, const int* in_sizes, int n_in,
                              void* d_out, int out_size, void* d_ws, size_t ws_size,
                              hipStream_t stream) {
  const float* x = (const float*)d_in[0];   // [256,1152,8] fp32
  const float* W = (const float*)d_in[1];   // [10,1152,8,16] fp32
  float* ws  = (float*)d_ws;                // 256*5120 fp32 partials (5.2 MB)
  float* out = (float*)d_out;               // 40960 fp32

  caps_gemm<<<dim3(NBLK), dim3(256), 0, stream>>>(x, W, ws);
  caps_reduce<<<dim3(80), dim3(128), 0, stream>>>(ws, out);
}